// Round 10
// baseline (353.115 us; speedup 1.0000x reference)
//
#include <hip/hip_runtime.h>
#include <hip/hip_bf16.h>
#include <stdint.h>

using hbf = __hip_bfloat16;
typedef __bf16 bf16x8 __attribute__((ext_vector_type(8)));
typedef float f32x4 __attribute__((ext_vector_type(4)));

#define MFMA16(a, b, c) __builtin_amdgcn_mfma_f32_16x16x32_bf16((a), (b), (c), 0, 0, 0)

__device__ __forceinline__ void async_copy16(const void* gsrc, void* ldst) {
  __builtin_amdgcn_global_load_lds((const __attribute__((address_space(1))) void*)gsrc,
                                   (__attribute__((address_space(3))) void*)ldst,
                                   16, 0, 0);
}

// ---------------- fused prep: 4 weight cast+transposes + LN0, one launch ----------------
__global__ __launch_bounds__(256) void prep_kernel(const float* __restrict__ W0a,
                                                   const float* __restrict__ W0b,
                                                   const float* __restrict__ W1a,
                                                   const float* __restrict__ W1b,
                                                   hbf* __restrict__ T0a, hbf* __restrict__ T0b,
                                                   hbf* __restrict__ T1a, hbf* __restrict__ T1b,
                                                   const float* __restrict__ x,
                                                   const float* __restrict__ g,
                                                   const float* __restrict__ bt,
                                                   hbf* __restrict__ h) {
  const int idx = blockIdx.x;
  const int tid = threadIdx.x;
  if (idx >= 1536) {  // ---- LN0: 4 rows/block ----
    const int row = (idx - 1536) * 4 + (tid >> 6);
    const int l = tid & 63;
    const float* xr = x + (size_t)row * 512;
    float v[8], s = 0.f, s2 = 0.f;
#pragma unroll
    for (int i = 0; i < 8; ++i) {
      float t = xr[l + 64 * i];
      v[i] = t; s += t; s2 += t * t;
    }
#pragma unroll
    for (int off = 32; off; off >>= 1) { s += __shfl_xor(s, off); s2 += __shfl_xor(s2, off); }
    float mu = s * (1.f / 512.f);
    float rs = rsqrtf(s2 * (1.f / 512.f) - mu * mu + 1e-3f);
    hbf* hr = h + (size_t)row * 512;
#pragma unroll
    for (int i = 0; i < 8; ++i) {
      int c = l + 64 * i;
      hr[c] = __float2bfloat16((v[i] - mu) * rs * g[c] + bt[c]);
    }
    return;
  }
  // ---- weight transpose ----
  __shared__ float tile[64][65];
  const float* W; hbf* Wt; int K, N, nt, i;
  if (idx < 256)        { W = W0a; Wt = T0a; K = 512;  N = 2048; nt = 32; i = idx; }
  else if (idx < 1024)  { W = W0b; Wt = T0b; K = 2048; N = 1536; nt = 24; i = idx - 256; }
  else if (idx < 1280)  { W = W1a; Wt = T1a; K = 512;  N = 2048; nt = 32; i = idx - 1024; }
  else                  { W = W1b; Wt = T1b; K = 2048; N = 512;  nt = 8;  i = idx - 1280; }
  const int n0 = (i % nt) * 64, k0 = (i / nt) * 64;
#pragma unroll
  for (int t = 0; t < 16; ++t) {
    int q = tid + t * 256;
    int r = q >> 6, c = q & 63;
    tile[r][c] = W[(size_t)(k0 + r) * N + n0 + c];
  }
  __syncthreads();
#pragma unroll
  for (int t = 0; t < 16; ++t) {
    int q = tid + t * 256;
    int r = q >> 6, c = q & 63;
    Wt[(size_t)(n0 + r) * K + k0 + c] = __float2bfloat16(tile[c][r]);
  }
}

// ---------------- residual add + LN1 (4 rows/block) ----------------
__global__ __launch_bounds__(256) void lnadd_kernel(const float* __restrict__ values,
                                                    const hbf* __restrict__ obuf,
                                                    const float* __restrict__ g,
                                                    const float* __restrict__ bt,
                                                    float* __restrict__ res1,
                                                    hbf* __restrict__ h2) {
  const int row = blockIdx.x * 4 + (threadIdx.x >> 6);
  const int l = threadIdx.x & 63;
  const float* vr = values + (size_t)row * 512;
  const hbf* orow = obuf + (size_t)row * 512;
  float* rr = res1 + (size_t)row * 512;
  float v[8], s = 0.f, s2 = 0.f;
#pragma unroll
  for (int i = 0; i < 8; ++i) {
    int c = l + 64 * i;
    float t = vr[c] + __bfloat162float(orow[c]);
    v[i] = t; s += t; s2 += t * t;
    rr[c] = t;
  }
#pragma unroll
  for (int off = 32; off; off >>= 1) { s += __shfl_xor(s, off); s2 += __shfl_xor(s2, off); }
  float mu = s * (1.f / 512.f);
  float rs = rsqrtf(s2 * (1.f / 512.f) - mu * mu + 1e-3f);
  hbf* hr = h2 + (size_t)row * 512;
#pragma unroll
  for (int i = 0; i < 8; ++i) {
    int c = l + 64 * i;
    hr[c] = __float2bfloat16((v[i] - mu) * rs * g[c] + bt[c]);
  }
}

// ---------------- GEMM: BM=128 BK=64; A via LDS dbuf, B DIRECT global->reg (L2-resident) ----
// Wave tile 32xBN (4x1 wave grid): A-rows read once per block; B on VMEM pipe, off LDS pipe.
// EPI 0: bf16 relu(acc+bias); EPI 1: bf16 acc+bias; EPI 2: f32 acc+bias+resid
// EPI 3: QKV epilogue -- q/k col-blocks -> X2 bf16, v col-blocks -> vT transposed
template <int EPI, int BN>
__global__ __launch_bounds__(256) void gemm_bt(const hbf* __restrict__ A,
                                               const hbf* __restrict__ Bt,
                                               const float* __restrict__ bias,
                                               const float* __restrict__ resid,
                                               void* __restrict__ outp,
                                               hbf* __restrict__ outp2,
                                               int M, int N, int K) {
  constexpr int MI = 2;            // 32 rows per wave
  constexpr int NJ = BN / 16;
  __shared__ hbf As[2][128 * 64];  // 2 x 16 KB
  const int tid = threadIdx.x;
  const int lane = tid & 63;
  const int w = tid >> 6;          // wave = m-stripe
  const int cq = lane >> 4, lr = lane & 15;

  // XCD-aware bijective swizzle (all grids are multiples of 8 blocks)
  const int nbx = gridDim.x;
  const int nwg = nbx * gridDim.y;
  const int bid = blockIdx.y * nbx + blockIdx.x;
  const int cpx = nwg >> 3;
  const int sw = (bid & 7) * cpx + (bid >> 3);
  const int m0 = (sw / nbx) * 128, n0 = (sw % nbx) * BN;

  f32x4 acc[MI][NJ] = {};

  // A staging: linear LDS dest, inverse-swizzled global source chunk
  int ar[4], ac[4];
#pragma unroll
  for (int p = 0; p < 4; ++p) {
    int off = p * 4096 + tid * 16;
    int r = off >> 7, sl = (off >> 4) & 7;
    ar[p] = r;
    ac[p] = sl ^ (r & 7);
  }

  auto stage = [&](int buf, int kt) {
#pragma unroll
    for (int p = 0; p < 4; ++p)
      async_copy16(A + (size_t)(m0 + ar[p]) * K + kt + ac[p] * 8,
                   (char*)As[buf] + p * 4096 + tid * 16);
  };

  // B row offsets (32-bit) for this lane's fragment rows
  int boff[NJ];
#pragma unroll
  for (int j = 0; j < NJ; ++j) boff[j] = (n0 + j * 16 + lr) * K + cq * 8;

  auto loadB = [&](bf16x8 (&bg)[2][NJ], int kt) {
#pragma unroll
    for (int kk = 0; kk < 2; ++kk)
#pragma unroll
      for (int j = 0; j < NJ; ++j)
        bg[kk][j] = *reinterpret_cast<const bf16x8*>(Bt + boff[j] + kt + kk * 32);
  };

  bf16x8 bg0[2][NJ], bg1[2][NJ];

  auto kstep = [&](int buf, int kt, bf16x8 (&bgCur)[2][NJ], bf16x8 (&bgNext)[2][NJ]) {
    if (kt + 64 < K) {
      stage(buf ^ 1, kt + 64);
      loadB(bgNext, kt + 64);
      // wait for cur tile's A staging (issued one kstep ago); 4 stage + 2*NJ B-loads newer
      if constexpr (BN == 64) asm volatile("s_waitcnt vmcnt(12)" ::: "memory");
      else                    asm volatile("s_waitcnt vmcnt(8)" ::: "memory");
    } else {
      asm volatile("s_waitcnt vmcnt(0)" ::: "memory");
    }
    __builtin_amdgcn_s_barrier();
    __builtin_amdgcn_sched_barrier(0);

    bf16x8 af[2][MI];
#pragma unroll
    for (int i = 0; i < MI; ++i) {
      int m = w * 32 + i * 16 + lr;
#pragma unroll
      for (int kk = 0; kk < 2; ++kk) {
        int sl = (kk * 4 + cq) ^ (m & 7);
        af[kk][i] = *reinterpret_cast<const bf16x8*>((const char*)As[buf] + m * 128 + sl * 16);
      }
    }
#pragma unroll
    for (int kk = 0; kk < 2; ++kk)
#pragma unroll
      for (int i = 0; i < MI; ++i)
#pragma unroll
        for (int j = 0; j < NJ; ++j)
          acc[i][j] = MFMA16(af[kk][i], bgCur[kk][j], acc[i][j]);

    __builtin_amdgcn_sched_barrier(0);
    __builtin_amdgcn_s_barrier();
  };

  stage(0, 0);
  loadB(bg0, 0);
  for (int kt = 0; kt < K; kt += 128) {  // all K are multiples of 128
    kstep(0, kt, bg0, bg1);
    kstep(1, kt + 64, bg1, bg0);
  }

  if (EPI == 3 && (n0 % 192) >= 128) {
    // v col-block: write transposed into vT[bh][d][s], 4 rows packed per 8B store
    const int hh = n0 / 192;
#pragma unroll
    for (int j = 0; j < NJ; ++j) {
      int col = n0 + j * 16 + lr;
      int d = (col % 192) - 128;
      float bcol = bias[col];
#pragma unroll
      for (int i = 0; i < MI; ++i) {
        int rowb = m0 + w * 32 + i * 16 + cq * 4;
        int bb_ = rowb >> 9, s0 = rowb & 511;
        unsigned short u[4];
#pragma unroll
        for (int r = 0; r < 4; ++r) {
          hbf t = __float2bfloat16(acc[i][j][r] + bcol);
          u[r] = *reinterpret_cast<unsigned short*>(&t);
        }
        uint2 pk;
        pk.x = (unsigned)u[0] | ((unsigned)u[1] << 16);
        pk.y = (unsigned)u[2] | ((unsigned)u[3] << 16);
        *reinterpret_cast<uint2*>(outp2 + ((size_t)(bb_ * 8 + hh) * 64 + d) * 512 + s0) = pk;
      }
    }
    return;
  }

#pragma unroll
  for (int j = 0; j < NJ; ++j) {
    int col = n0 + j * 16 + lr;
    float bcol = bias[col];
#pragma unroll
    for (int i = 0; i < MI; ++i) {
      int rowb = m0 + w * 32 + i * 16 + cq * 4;
#pragma unroll
      for (int r = 0; r < 4; ++r) {
        int row = rowb + r;
        float v = acc[i][j][r] + bcol;
        if (EPI == 0) {
          v = v > 0.f ? v : 0.f;
          ((hbf*)outp)[(size_t)row * N + col] = __float2bfloat16(v);
        } else if (EPI == 1 || EPI == 3) {
          ((hbf*)outp)[(size_t)row * N + col] = __float2bfloat16(v);
        } else {
          ((float*)outp)[(size_t)row * N + col] = v + resid[(size_t)row * N + col];
        }
      }
    }
  }
}

// ---------------- causal flash attention, fused pos-bias, static-max softmax ----------------
__global__ __launch_bounds__(256) void attn_kernel(const hbf* __restrict__ X2,
                                                   const hbf* __restrict__ vT,
                                                   const float* __restrict__ Wp,
                                                   const float* __restrict__ bp,
                                                   hbf* __restrict__ obuf) {
  __shared__ float bias_lds[2][64];
  __shared__ hbf p_lds[4][16][32];
  // XCD swizzle: co-locate the 8 q-tiles of one bh on one XCD (K/V L2 reuse)
  const int wid = blockIdx.y * 64 + blockIdx.x;
  const int bh = ((wid & 7) << 3) | ((wid >> 3) & 7);
  const int q0 = (wid >> 6) * 64;
  const int b = bh >> 3, h = bh & 7;
  const int tid = threadIdx.x;
  const int lane = tid & 63, w = tid >> 6;
  const int qbase = q0 + w * 16;

  if (tid < 128) {
    int c = tid >> 6, qq = tid & 63;
    const hbf* qp = X2 + (size_t)(b * 512 + q0 + qq) * 1536 + h * 192;
    const float* wr = Wp + c * 512 + h * 64;
    const float* br = bp + h * 64;
    float s = 0.f;
#pragma unroll
    for (int d8 = 0; d8 < 8; ++d8) {
      bf16x8 qv = *reinterpret_cast<const bf16x8*>(qp + d8 * 8);
#pragma unroll
      for (int j = 0; j < 8; ++j) s += (float)qv[j] * (wr[d8 * 8 + j] + br[d8 * 8 + j]);
    }
    bias_lds[c][qq] = s;
  }

  bf16x8 qa[2];
  {
    int qrow = qbase + (lane & 15);
    const hbf* qp = X2 + (size_t)(b * 512 + qrow) * 1536 + h * 192 + (lane >> 4) * 8;
#pragma unroll
    for (int c = 0; c < 2; ++c) qa[c] = *reinterpret_cast<const bf16x8*>(qp + c * 32);
  }
  __syncthreads();

  float bias0[4], bias1[4];
#pragma unroll
  for (int r = 0; r < 4; ++r) {
    int qq = w * 16 + (lane >> 4) * 4 + r;
    bias0[r] = bias_lds[0][qq];
    bias1[r] = bias_lds[1][qq];
  }

  const float MAXS = 16.f;
  float lsum[4] = {0.f, 0.f, 0.f, 0.f};
  f32x4 oacc[4];
#pragma unroll
  for (int nt = 0; nt < 4; ++nt) oacc[nt] = (f32x4){0.f, 0.f, 0.f, 0.f};

  const int qhi = qbase + 15;
  const int nchunks = (qhi >> 5) + 1;
  for (int ch = 0; ch < nchunks; ++ch) {
    const int k32 = ch * 32;
    f32x4 z = {0.f, 0.f, 0.f, 0.f};
    f32x4 s0, s1;
    {
      const hbf* kp = X2 + (size_t)(b * 512 + k32 + (lane & 15)) * 1536 + h * 192 + 64 + (lane >> 4) * 8;
      bf16x8 kb = *reinterpret_cast<const bf16x8*>(kp);
      s0 = MFMA16(qa[0], kb, z);
      kb = *reinterpret_cast<const bf16x8*>(kp + 32);
      s0 = MFMA16(qa[1], kb, s0);
      const hbf* kp1 = kp + 16 * 1536;
      kb = *reinterpret_cast<const bf16x8*>(kp1);
      s1 = MFMA16(qa[0], kb, z);
      kb = *reinterpret_cast<const bf16x8*>(kp1 + 32);
      s1 = MFMA16(qa[1], kb, s1);
    }
    const int col0 = k32 + (lane & 15);
    const int col1 = col0 + 16;
#pragma unroll
    for (int r = 0; r < 4; ++r) {
      int q = qbase + (lane >> 4) * 4 + r;
      float sc0 = (col0 > q) ? -1e30f : (s0[r] * 0.125f + (col0 == q ? bias1[r] : bias0[r]));
      float sc1 = (col1 > q) ? -1e30f : (s1[r] * 0.125f + (col1 == q ? bias1[r] : bias0[r]));
      float p0 = __expf(sc0 - MAXS);
      float p1 = __expf(sc1 - MAXS);
      lsum[r] += p0 + p1;
      p_lds[w][(lane >> 4) * 4 + r][lane & 15] = __float2bfloat16(p0);
      p_lds[w][(lane >> 4) * 4 + r][16 + (lane & 15)] = __float2bfloat16(p1);
    }
    bf16x8 pa = *reinterpret_cast<const bf16x8*>(&p_lds[w][lane & 15][(lane >> 4) * 8]);
#pragma unroll
    for (int nt = 0; nt < 4; ++nt) {
      const hbf* vp = vT + ((size_t)bh * 64 + nt * 16 + (lane & 15)) * 512 + k32 + (lane >> 4) * 8;
      bf16x8 vb = *reinterpret_cast<const bf16x8*>(vp);
      oacc[nt] = MFMA16(pa, vb, oacc[nt]);
    }
  }
#pragma unroll
  for (int r = 0; r < 4; ++r) {
#pragma unroll
    for (int off = 1; off < 16; off <<= 1) lsum[r] += __shfl_xor(lsum[r], off);
    float rl = 1.f / lsum[r];
    int q = qbase + (lane >> 4) * 4 + r;
    hbf* orow = obuf + (size_t)(b * 512 + q) * 512 + h * 64;
#pragma unroll
    for (int nt = 0; nt < 4; ++nt) orow[nt * 16 + (lane & 15)] = __float2bfloat16(oacc[nt][r] * rl);
  }
}

extern "C" void kernel_launch(void* const* d_in, const int* in_sizes, int n_in,
                              void* d_out, int out_size, void* d_ws, size_t ws_size,
                              hipStream_t stream) {
  const float* values = (const float*)d_in[0];
  const float* ln0_g = (const float*)d_in[2];
  const float* ln0_b = (const float*)d_in[3];
  const float* W0a = (const float*)d_in[4];
  const float* b0a = (const float*)d_in[5];
  const float* W0b = (const float*)d_in[6];
  const float* b0b = (const float*)d_in[7];
  const float* Wp = (const float*)d_in[8];
  const float* bp = (const float*)d_in[9];
  const float* ln1_g = (const float*)d_in[10];
  const float* ln1_b = (const float*)d_in[11];
  const float* W1a = (const float*)d_in[12];
  const float* b1a = (const float*)d_in[13];
  const float* W1b = (const float*)d_in[14];
  const float* b1b = (const float*)d_in[15];

  char* ws = (char*)d_ws;
  hbf* W0a_t = (hbf*)(ws + (0ull << 20));
  hbf* W0b_t = (hbf*)(ws + (2ull << 20));
  hbf* W1a_t = (hbf*)(ws + (8ull << 20));
  hbf* W1b_t = (hbf*)(ws + (10ull << 20));
  hbf* hbuf = (hbf*)(ws + (12ull << 20));   // LN0 out, reused as h2
  hbf* X1 = (hbf*)(ws + (16ull << 20));     // 16MB, reused as X3
  hbf* X2 = (hbf*)(ws + (32ull << 20));     // 12MB (QKV; v cols unused)
  hbf* obuf = (hbf*)(ws + (44ull << 20));   // 4MB bf16
  hbf* vT = (hbf*)(ws + (52ull << 20));     // 4MB
  float* res1 = (float*)(ws + (57ull << 20));  // 8MB
  hbf* X3 = X1;
  hbf* h2 = hbuf;

  prep_kernel<<<2560, 256, 0, stream>>>(W0a, W0b, W1a, W1b, W0a_t, W0b_t, W1a_t, W1b_t,
                                        values, ln0_g, ln0_b, hbuf);

  gemm_bt<0, 64><<<dim3(32, 32), 256, 0, stream>>>(hbuf, W0a_t, b0a, nullptr, X1, nullptr, 4096, 2048, 512);
  gemm_bt<3, 64><<<dim3(24, 32), 256, 0, stream>>>(X1, W0b_t, b0b, nullptr, X2, vT, 4096, 1536, 2048);

  attn_kernel<<<dim3(64, 8), 256, 0, stream>>>(X2, vT, Wp, bp, obuf);

  lnadd_kernel<<<1024, 256, 0, stream>>>(values, obuf, ln1_g, ln1_b, res1, h2);

  gemm_bt<0, 64><<<dim3(32, 32), 256, 0, stream>>>(h2, W1a_t, b1a, nullptr, X3, nullptr, 4096, 2048, 512);
  gemm_bt<2, 32><<<dim3(16, 32), 256, 0, stream>>>(X3, W1b_t, b1b, res1, (float*)d_out, nullptr, 4096, 512, 2048);
}

// Round 11
// 224.673 us; speedup vs baseline: 1.5717x; 1.5717x over previous
//
#include <hip/hip_runtime.h>
#include <hip/hip_bf16.h>
#include <stdint.h>

using hbf = __hip_bfloat16;
typedef __bf16 bf16x8 __attribute__((ext_vector_type(8)));
typedef float f32x4 __attribute__((ext_vector_type(4)));

#define MFMA16(a, b, c) __builtin_amdgcn_mfma_f32_16x16x32_bf16((a), (b), (c), 0, 0, 0)

__device__ __forceinline__ void async_copy16(const void* gsrc, void* ldst) {
  __builtin_amdgcn_global_load_lds((const __attribute__((address_space(1))) void*)gsrc,
                                   (__attribute__((address_space(3))) void*)ldst,
                                   16, 0, 0);
}

// ---------------- fused prep: 4 weight cast+transposes + LN0, one launch ----------------
__global__ __launch_bounds__(256) void prep_kernel(const float* __restrict__ W0a,
                                                   const float* __restrict__ W0b,
                                                   const float* __restrict__ W1a,
                                                   const float* __restrict__ W1b,
                                                   hbf* __restrict__ T0a, hbf* __restrict__ T0b,
                                                   hbf* __restrict__ T1a, hbf* __restrict__ T1b,
                                                   const float* __restrict__ x,
                                                   const float* __restrict__ g,
                                                   const float* __restrict__ bt,
                                                   hbf* __restrict__ h) {
  const int idx = blockIdx.x;
  const int tid = threadIdx.x;
  if (idx >= 1536) {  // ---- LN0: 4 rows/block ----
    const int row = (idx - 1536) * 4 + (tid >> 6);
    const int l = tid & 63;
    const float* xr = x + (size_t)row * 512;
    float v[8], s = 0.f, s2 = 0.f;
#pragma unroll
    for (int i = 0; i < 8; ++i) {
      float t = xr[l + 64 * i];
      v[i] = t; s += t; s2 += t * t;
    }
#pragma unroll
    for (int off = 32; off; off >>= 1) { s += __shfl_xor(s, off); s2 += __shfl_xor(s2, off); }
    float mu = s * (1.f / 512.f);
    float rs = rsqrtf(s2 * (1.f / 512.f) - mu * mu + 1e-3f);
    hbf* hr = h + (size_t)row * 512;
#pragma unroll
    for (int i = 0; i < 8; ++i) {
      int c = l + 64 * i;
      hr[c] = __float2bfloat16((v[i] - mu) * rs * g[c] + bt[c]);
    }
    return;
  }
  // ---- weight transpose ----
  __shared__ float tile[64][65];
  const float* W; hbf* Wt; int K, N, nt, i;
  if (idx < 256)        { W = W0a; Wt = T0a; K = 512;  N = 2048; nt = 32; i = idx; }
  else if (idx < 1024)  { W = W0b; Wt = T0b; K = 2048; N = 1536; nt = 24; i = idx - 256; }
  else if (idx < 1280)  { W = W1a; Wt = T1a; K = 512;  N = 2048; nt = 32; i = idx - 1024; }
  else                  { W = W1b; Wt = T1b; K = 2048; N = 512;  nt = 8;  i = idx - 1280; }
  const int n0 = (i % nt) * 64, k0 = (i / nt) * 64;
#pragma unroll
  for (int t = 0; t < 16; ++t) {
    int q = tid + t * 256;
    int r = q >> 6, c = q & 63;
    tile[r][c] = W[(size_t)(k0 + r) * N + n0 + c];
  }
  __syncthreads();
#pragma unroll
  for (int t = 0; t < 16; ++t) {
    int q = tid + t * 256;
    int r = q >> 6, c = q & 63;
    Wt[(size_t)(n0 + r) * K + k0 + c] = __float2bfloat16(tile[c][r]);
  }
}

// ---------------- residual add + LN1 (4 rows/block) ----------------
__global__ __launch_bounds__(256) void lnadd_kernel(const float* __restrict__ values,
                                                    const hbf* __restrict__ obuf,
                                                    const float* __restrict__ g,
                                                    const float* __restrict__ bt,
                                                    float* __restrict__ res1,
                                                    hbf* __restrict__ h2) {
  const int row = blockIdx.x * 4 + (threadIdx.x >> 6);
  const int l = threadIdx.x & 63;
  const float* vr = values + (size_t)row * 512;
  const hbf* orow = obuf + (size_t)row * 512;
  float* rr = res1 + (size_t)row * 512;
  float v[8], s = 0.f, s2 = 0.f;
#pragma unroll
  for (int i = 0; i < 8; ++i) {
    int c = l + 64 * i;
    float t = vr[c] + __bfloat162float(orow[c]);
    v[i] = t; s += t; s2 += t * t;
    rr[c] = t;
  }
#pragma unroll
  for (int off = 32; off; off >>= 1) { s += __shfl_xor(s, off); s2 += __shfl_xor(s2, off); }
  float mu = s * (1.f / 512.f);
  float rs = rsqrtf(s2 * (1.f / 512.f) - mu * mu + 1e-3f);
  hbf* hr = h2 + (size_t)row * 512;
#pragma unroll
  for (int i = 0; i < 8; ++i) {
    int c = l + 64 * i;
    hr[c] = __float2bfloat16((v[i] - mu) * rs * g[c] + bt[c]);
  }
}

// ---------------- GEMM: BM=128 BK=64, LDS dbuf A+B, counted vmcnt (round-9 structure) ----
// EPI 0: bf16 relu(acc+bias); EPI 1: bf16 acc+bias; EPI 2: f32 acc+bias+resid
// EPI 3: QKV epilogue -- q/k col-blocks -> X2 bf16, v col-blocks -> vT transposed
template <int EPI, int BN>
__global__ __launch_bounds__(256) void gemm_bt(const hbf* __restrict__ A,
                                               const hbf* __restrict__ Bt,
                                               const float* __restrict__ bias,
                                               const float* __restrict__ resid,
                                               void* __restrict__ outp,
                                               hbf* __restrict__ outp2,
                                               int M, int N, int K) {
  constexpr int WCOLS = (BN == 64) ? 2 : 1;
  constexpr int WROWS = 4 / WCOLS;
  constexpr int MI = 128 / (WROWS * 16);
  constexpr int NJ = BN / (WCOLS * 16);
  constexpr int BCH = BN / 32;  // B staging chunks per thread
  __shared__ hbf As[2][128 * 64];
  __shared__ hbf Bs[2][BN * 64];
  const int tid = threadIdx.x;
  const int lane = tid & 63;
  const int w = tid >> 6;
  const int wm = w / WCOLS, wn = w % WCOLS;

  // XCD-aware bijective swizzle (all grids are multiples of 8 blocks)
  const int nbx = gridDim.x;
  const int nwg = nbx * gridDim.y;
  const int bid = blockIdx.y * nbx + blockIdx.x;
  const int cpx = nwg >> 3;
  const int sw = (bid & 7) * cpx + (bid >> 3);
  const int m0 = (sw / nbx) * 128, n0 = (sw % nbx) * BN;

  f32x4 acc[MI][NJ] = {};

  int ar[4], ac[4];
#pragma unroll
  for (int p = 0; p < 4; ++p) {
    int off = p * 4096 + tid * 16;
    int r = off >> 7, sl = (off >> 4) & 7;
    ar[p] = r;
    ac[p] = sl ^ (r & 7);
  }

  auto stage = [&](int buf, int kt) {
#pragma unroll
    for (int p = 0; p < 4; ++p)
      async_copy16(A + (size_t)(m0 + ar[p]) * K + kt + ac[p] * 8,
                   (char*)As[buf] + p * 4096 + tid * 16);
#pragma unroll
    for (int p = 0; p < BCH; ++p)
      async_copy16(Bt + (size_t)(n0 + ar[p]) * K + kt + ac[p] * 8,
                   (char*)Bs[buf] + p * 4096 + tid * 16);
  };

  stage(0, 0);
  int cur = 0;

  for (int kt = 0; kt < K; kt += 64) {
    if (kt + 64 < K) {
      stage(cur ^ 1, kt + 64);
      if constexpr (BN == 64) asm volatile("s_waitcnt vmcnt(6)" ::: "memory");
      else                    asm volatile("s_waitcnt vmcnt(5)" ::: "memory");
    } else {
      asm volatile("s_waitcnt vmcnt(0)" ::: "memory");
    }
    __builtin_amdgcn_s_barrier();
    __builtin_amdgcn_sched_barrier(0);

    const int cq = lane >> 4, lr = lane & 15;
    bf16x8 af[2][MI], bg[2][NJ];
#pragma unroll
    for (int i = 0; i < MI; ++i) {
      int m = wm * (MI * 16) + i * 16 + lr;
#pragma unroll
      for (int kk = 0; kk < 2; ++kk) {
        int sl = (kk * 4 + cq) ^ (m & 7);
        af[kk][i] = *reinterpret_cast<const bf16x8*>((const char*)As[cur] + m * 128 + sl * 16);
      }
    }
#pragma unroll
    for (int j = 0; j < NJ; ++j) {
      int n = wn * (NJ * 16) + j * 16 + lr;
#pragma unroll
      for (int kk = 0; kk < 2; ++kk) {
        int sl = (kk * 4 + cq) ^ (n & 7);
        bg[kk][j] = *reinterpret_cast<const bf16x8*>((const char*)Bs[cur] + n * 128 + sl * 16);
      }
    }
#pragma unroll
    for (int kk = 0; kk < 2; ++kk)
#pragma unroll
      for (int i = 0; i < MI; ++i)
#pragma unroll
        for (int j = 0; j < NJ; ++j)
          acc[i][j] = MFMA16(af[kk][i], bg[kk][j], acc[i][j]);

    __builtin_amdgcn_sched_barrier(0);
    __builtin_amdgcn_s_barrier();
    cur ^= 1;
  }

  const int lr = lane & 15;
  if (EPI == 3 && (n0 % 192) >= 128) {
    // v col-block: write transposed into vT[bh][d][s], 4 rows packed per 8B store
    const int hh = n0 / 192;
#pragma unroll
    for (int j = 0; j < NJ; ++j) {
      int col = n0 + wn * (NJ * 16) + j * 16 + lr;
      int d = (col % 192) - 128;
      float bcol = bias[col];
#pragma unroll
      for (int i = 0; i < MI; ++i) {
        int rowb = m0 + wm * (MI * 16) + i * 16 + (lane >> 4) * 4;
        int bb_ = rowb >> 9, s0 = rowb & 511;
        unsigned short u[4];
#pragma unroll
        for (int r = 0; r < 4; ++r) {
          hbf t = __float2bfloat16(acc[i][j][r] + bcol);
          u[r] = *reinterpret_cast<unsigned short*>(&t);
        }
        uint2 pk;
        pk.x = (unsigned)u[0] | ((unsigned)u[1] << 16);
        pk.y = (unsigned)u[2] | ((unsigned)u[3] << 16);
        *reinterpret_cast<uint2*>(outp2 + ((size_t)(bb_ * 8 + hh) * 64 + d) * 512 + s0) = pk;
      }
    }
    return;
  }

#pragma unroll
  for (int j = 0; j < NJ; ++j) {
    int col = n0 + wn * (NJ * 16) + j * 16 + lr;
    float bcol = bias[col];
#pragma unroll
    for (int i = 0; i < MI; ++i) {
      int rowb = m0 + wm * (MI * 16) + i * 16 + (lane >> 4) * 4;
#pragma unroll
      for (int r = 0; r < 4; ++r) {
        int row = rowb + r;
        float v = acc[i][j][r] + bcol;
        if (EPI == 0) {
          v = v > 0.f ? v : 0.f;
          ((hbf*)outp)[(size_t)row * N + col] = __float2bfloat16(v);
        } else if (EPI == 1 || EPI == 3) {
          ((hbf*)outp)[(size_t)row * N + col] = __float2bfloat16(v);
        } else {
          ((float*)outp)[(size_t)row * N + col] = v + resid[(size_t)row * N + col];
        }
      }
    }
  }
}

// ---------------- causal flash attention, fused pos-bias, static-max softmax ----------------
__global__ __launch_bounds__(256) void attn_kernel(const hbf* __restrict__ X2,
                                                   const hbf* __restrict__ vT,
                                                   const float* __restrict__ Wp,
                                                   const float* __restrict__ bp,
                                                   hbf* __restrict__ obuf) {
  __shared__ float bias_lds[2][64];
  __shared__ hbf p_lds[4][16][32];
  // XCD swizzle: co-locate the 8 q-tiles of one bh on one XCD (K/V L2 reuse)
  const int wid = blockIdx.y * 64 + blockIdx.x;
  const int bh = ((wid & 7) << 3) | ((wid >> 3) & 7);
  const int q0 = (wid >> 6) * 64;
  const int b = bh >> 3, h = bh & 7;
  const int tid = threadIdx.x;
  const int lane = tid & 63, w = tid >> 6;
  const int qbase = q0 + w * 16;

  if (tid < 128) {
    int c = tid >> 6, qq = tid & 63;
    const hbf* qp = X2 + (size_t)(b * 512 + q0 + qq) * 1536 + h * 192;
    const float* wr = Wp + c * 512 + h * 64;
    const float* br = bp + h * 64;
    float s = 0.f;
#pragma unroll
    for (int d8 = 0; d8 < 8; ++d8) {
      bf16x8 qv = *reinterpret_cast<const bf16x8*>(qp + d8 * 8);
#pragma unroll
      for (int j = 0; j < 8; ++j) s += (float)qv[j] * (wr[d8 * 8 + j] + br[d8 * 8 + j]);
    }
    bias_lds[c][qq] = s;
  }

  bf16x8 qa[2];
  {
    int qrow = qbase + (lane & 15);
    const hbf* qp = X2 + (size_t)(b * 512 + qrow) * 1536 + h * 192 + (lane >> 4) * 8;
#pragma unroll
    for (int c = 0; c < 2; ++c) qa[c] = *reinterpret_cast<const bf16x8*>(qp + c * 32);
  }
  __syncthreads();

  float bias0[4], bias1[4];
#pragma unroll
  for (int r = 0; r < 4; ++r) {
    int qq = w * 16 + (lane >> 4) * 4 + r;
    bias0[r] = bias_lds[0][qq];
    bias1[r] = bias_lds[1][qq];
  }

  const float MAXS = 16.f;
  float lsum[4] = {0.f, 0.f, 0.f, 0.f};
  f32x4 oacc[4];
#pragma unroll
  for (int nt = 0; nt < 4; ++nt) oacc[nt] = (f32x4){0.f, 0.f, 0.f, 0.f};

  const int qhi = qbase + 15;
  const int nchunks = (qhi >> 5) + 1;
  for (int ch = 0; ch < nchunks; ++ch) {
    const int k32 = ch * 32;
    f32x4 z = {0.f, 0.f, 0.f, 0.f};
    f32x4 s0, s1;
    {
      const hbf* kp = X2 + (size_t)(b * 512 + k32 + (lane & 15)) * 1536 + h * 192 + 64 + (lane >> 4) * 8;
      bf16x8 kb = *reinterpret_cast<const bf16x8*>(kp);
      s0 = MFMA16(qa[0], kb, z);
      kb = *reinterpret_cast<const bf16x8*>(kp + 32);
      s0 = MFMA16(qa[1], kb, s0);
      const hbf* kp1 = kp + 16 * 1536;
      kb = *reinterpret_cast<const bf16x8*>(kp1);
      s1 = MFMA16(qa[0], kb, z);
      kb = *reinterpret_cast<const bf16x8*>(kp1 + 32);
      s1 = MFMA16(qa[1], kb, s1);
    }
    const int col0 = k32 + (lane & 15);
    const int col1 = col0 + 16;
#pragma unroll
    for (int r = 0; r < 4; ++r) {
      int q = qbase + (lane >> 4) * 4 + r;
      float sc0 = (col0 > q) ? -1e30f : (s0[r] * 0.125f + (col0 == q ? bias1[r] : bias0[r]));
      float sc1 = (col1 > q) ? -1e30f : (s1[r] * 0.125f + (col1 == q ? bias1[r] : bias0[r]));
      float p0 = __expf(sc0 - MAXS);
      float p1 = __expf(sc1 - MAXS);
      lsum[r] += p0 + p1;
      p_lds[w][(lane >> 4) * 4 + r][lane & 15] = __float2bfloat16(p0);
      p_lds[w][(lane >> 4) * 4 + r][16 + (lane & 15)] = __float2bfloat16(p1);
    }
    bf16x8 pa = *reinterpret_cast<const bf16x8*>(&p_lds[w][lane & 15][(lane >> 4) * 8]);
#pragma unroll
    for (int nt = 0; nt < 4; ++nt) {
      const hbf* vp = vT + ((size_t)bh * 64 + nt * 16 + (lane & 15)) * 512 + k32 + (lane >> 4) * 8;
      bf16x8 vb = *reinterpret_cast<const bf16x8*>(vp);
      oacc[nt] = MFMA16(pa, vb, oacc[nt]);
    }
  }
#pragma unroll
  for (int r = 0; r < 4; ++r) {
#pragma unroll
    for (int off = 1; off < 16; off <<= 1) lsum[r] += __shfl_xor(lsum[r], off);
    float rl = 1.f / lsum[r];
    int q = qbase + (lane >> 4) * 4 + r;
    hbf* orow = obuf + (size_t)(b * 512 + q) * 512 + h * 64;
#pragma unroll
    for (int nt = 0; nt < 4; ++nt) orow[nt * 16 + (lane & 15)] = __float2bfloat16(oacc[nt][r] * rl);
  }
}

extern "C" void kernel_launch(void* const* d_in, const int* in_sizes, int n_in,
                              void* d_out, int out_size, void* d_ws, size_t ws_size,
                              hipStream_t stream) {
  const float* values = (const float*)d_in[0];
  const float* ln0_g = (const float*)d_in[2];
  const float* ln0_b = (const float*)d_in[3];
  const float* W0a = (const float*)d_in[4];
  const float* b0a = (const float*)d_in[5];
  const float* W0b = (const float*)d_in[6];
  const float* b0b = (const float*)d_in[7];
  const float* Wp = (const float*)d_in[8];
  const float* bp = (const float*)d_in[9];
  const float* ln1_g = (const float*)d_in[10];
  const float* ln1_b = (const float*)d_in[11];
  const float* W1a = (const float*)d_in[12];
  const float* b1a = (const float*)d_in[13];
  const float* W1b = (const float*)d_in[14];
  const float* b1b = (const float*)d_in[15];

  char* ws = (char*)d_ws;
  hbf* W0a_t = (hbf*)(ws + (0ull << 20));
  hbf* W0b_t = (hbf*)(ws + (2ull << 20));
  hbf* W1a_t = (hbf*)(ws + (8ull << 20));
  hbf* W1b_t = (hbf*)(ws + (10ull << 20));
  hbf* hbuf = (hbf*)(ws + (12ull << 20));   // LN0 out, reused as h2
  hbf* X1 = (hbf*)(ws + (16ull << 20));     // 16MB, reused as X3
  hbf* X2 = (hbf*)(ws + (32ull << 20));     // 12MB (QKV; v cols unused)
  hbf* obuf = (hbf*)(ws + (44ull << 20));   // 4MB bf16
  hbf* vT = (hbf*)(ws + (52ull << 20));     // 4MB
  float* res1 = (float*)(ws + (57ull << 20));  // 8MB
  hbf* X3 = X1;
  hbf* h2 = hbuf;

  prep_kernel<<<2560, 256, 0, stream>>>(W0a, W0b, W1a, W1b, W0a_t, W0b_t, W1a_t, W1b_t,
                                        values, ln0_g, ln0_b, hbuf);

  gemm_bt<0, 64><<<dim3(32, 32), 256, 0, stream>>>(hbuf, W0a_t, b0a, nullptr, X1, nullptr, 4096, 2048, 512);
  gemm_bt<3, 64><<<dim3(24, 32), 256, 0, stream>>>(X1, W0b_t, b0b, nullptr, X2, vT, 4096, 1536, 2048);

  attn_kernel<<<dim3(64, 8), 256, 0, stream>>>(X2, vT, Wp, bp, obuf);

  lnadd_kernel<<<1024, 256, 0, stream>>>(values, obuf, ln1_g, ln1_b, res1, h2);

  gemm_bt<0, 64><<<dim3(32, 32), 256, 0, stream>>>(h2, W1a_t, b1a, nullptr, X3, nullptr, 4096, 2048, 512);
  gemm_bt<2, 32><<<dim3(16, 32), 256, 0, stream>>>(X3, W1b_t, b1b, res1, (float*)d_out, nullptr, 4096, 512, 2048);
}